// Round 3
// baseline (110002.649 us; speedup 1.0000x reference)
//
#include <hip/hip_runtime.h>
#include <math.h>

// ---------------------------------------------------------------------------
// SimAM-CNN + Mogrifier-LSTM (Round 3): persistent single-kernel LSTM with
// device-scope grid barriers (was: 12 launches/step x 128 steps).
// B=128, T=128, D=64; LSTM IN=4096, H=256, 128 steps, 3 mogrifier rounds.
// xl[b,t,:] = z + b*524288 + t*4096 (flat NCHW reinterpret).
// ---------------------------------------------------------------------------

typedef unsigned short u16;

#define EPSBN 1e-5f

__device__ __forceinline__ float sigf(float x) { return 1.0f / (1.0f + expf(-x)); }

__device__ __forceinline__ float b2f(u16 u) {
  union { unsigned int i; float f; } v; v.i = ((unsigned int)u) << 16; return v.f;
}
__device__ __forceinline__ u16 f2b(float f) {
  union { float f; unsigned int i; } v; v.f = f;
  unsigned int r = v.i + 0x7FFFu + ((v.i >> 16) & 1u);
  return (u16)(r >> 16);
}

template <typename T> __device__ __forceinline__ float ld1(const T* p);
template <> __device__ __forceinline__ float ld1<float>(const float* p) { return *p; }
template <> __device__ __forceinline__ float ld1<u16>(const u16* p) { return b2f(*p); }
template <typename T> __device__ __forceinline__ void st1(T* p, float v);
template <> __device__ __forceinline__ void st1<float>(float* p, float v) { *p = v; }
template <> __device__ __forceinline__ void st1<u16>(u16* p, float v) { *p = f2b(v); }

__device__ __forceinline__ float simam_elem(float xv, float s, float ss) {
  float mu = (s - xv) * (1.0f / 8191.0f);
  float var = (ss - xv * xv - 8191.0f * mu * mu) * (1.0f / 8190.0f);
  float einv = ((xv - mu) * (xv - mu) + 2.0f * var + 0.2f) / (4.0f * (var + 0.1f));
  return xv * sigf(einv);
}

// --------------------------- CNN stage 1 (unchanged, passed R2) -------------
__global__ __launch_bounds__(256) void k_conv1(
    const float* __restrict__ x,
    const float* __restrict__ w1a, const float* __restrict__ b1a,
    const float* __restrict__ g1a, const float* __restrict__ bb1a,
    const float* __restrict__ m1a, const float* __restrict__ v1a,
    const float* __restrict__ w1b, const float* __restrict__ b1b,
    const float* __restrict__ g1b, const float* __restrict__ bb1b,
    const float* __restrict__ m1b, const float* __restrict__ v1b,
    u16* __restrict__ y1u, float* __restrict__ ps1, float* __restrict__ pss1)
{
  __shared__ float xs[6][66];
  __shared__ float a1[32][6][66];
  __shared__ float A1[32], T1[32], S2[32], T2[32];
  __shared__ float reds[4][32], redq[4][32];
  const int tid = threadIdx.x;
  const int b = blockIdx.x, t0 = blockIdx.y * 4;
  if (tid < 32) {
    float s = g1a[tid] * rsqrtf(v1a[tid] + EPSBN);
    A1[tid] = w1a[tid] * s;
    T1[tid] = (b1a[tid] - m1a[tid]) * s + bb1a[tid];
    float s2 = g1b[tid] * rsqrtf(v1b[tid] + EPSBN);
    S2[tid] = s2;
    T2[tid] = (b1b[tid] - m1b[tid]) * s2 + bb1b[tid];
  }
  for (int i = tid; i < 6 * 66; i += 256) {
    int r = i / 66, cc = i - r * 66;
    int t = t0 + r - 1, d = cc - 1;
    float v = 0.f;
    if (t >= 0 && t < 128 && d >= 0 && d < 64) v = x[(b * 128 + t) * 64 + d];
    xs[r][cc] = v;
  }
  __syncthreads();
  for (int i = tid; i < 32 * 6 * 66; i += 256) {
    int c = i / 396;
    int rr = i - c * 396;
    int r = rr / 66, cc = rr - r * 66;
    int t = t0 + r - 1, d = cc - 1;
    float v = 0.f;
    if (t >= 0 && t < 128 && d >= 0 && d < 64)
      v = fmaxf(xs[r][cc] * A1[c] + T1[c], 0.f);
    a1[c][r][cc] = v;
  }
  __syncthreads();
  const int d = tid & 63, tq = tid >> 6, lane = tid & 63;
  float acc[32];
#pragma unroll
  for (int i = 0; i < 32; ++i) acc[i] = 0.f;
#pragma unroll 1
  for (int c1 = 0; c1 < 32; ++c1) {
#pragma unroll
    for (int dt = 0; dt < 3; ++dt) {
      float av0 = a1[c1][tq + dt][d];
      float av1 = a1[c1][tq + dt][d + 1];
      float av2 = a1[c1][tq + dt][d + 2];
#pragma unroll
      for (int c2 = 0; c2 < 32; ++c2) {
        const float* wp = w1b + ((c2 * 32 + c1) * 3 + dt) * 3;  // uniform
        acc[c2] += av0 * wp[0] + av1 * wp[1] + av2 * wp[2];
      }
    }
  }
  const size_t ob = (size_t)b * 32 * 8192 + (size_t)(t0 + tq) * 64 + d;
#pragma unroll
  for (int c2 = 0; c2 < 32; ++c2) {
    float v = fmaxf(acc[c2] * S2[c2] + T2[c2], 0.f);
    y1u[ob + (size_t)c2 * 8192] = f2b(v);
    float s = v, q = v * v;
#pragma unroll
    for (int off = 32; off; off >>= 1) {
      s += __shfl_down(s, off);
      q += __shfl_down(q, off);
    }
    if (lane == 0) { reds[tq][c2] = s; redq[tq][c2] = q; }
  }
  __syncthreads();
  if (tid < 32) {
    float s = (reds[0][tid] + reds[1][tid]) + (reds[2][tid] + reds[3][tid]);
    float q = (redq[0][tid] + redq[1][tid]) + (redq[2][tid] + redq[3][tid]);
    ps1[(size_t)((b * 32 + tid) << 5) + blockIdx.y] = s;
    pss1[(size_t)((b * 32 + tid) << 5) + blockIdx.y] = q;
  }
}

__global__ __launch_bounds__(256) void k_red(
    const float* __restrict__ ps, const float* __restrict__ pss,
    float* __restrict__ stats, int npart, int nplanes)
{
  int p = blockIdx.x * 256 + threadIdx.x;
  if (p >= nplanes) return;
  float s = 0.f, q = 0.f;
  for (int j = 0; j < npart; ++j) {
    s += ps[(size_t)p * npart + j];
    q += pss[(size_t)p * npart + j];
  }
  stats[p] = s;
  stats[nplanes + p] = q;
}

template <typename T>
__global__ __launch_bounds__(256) void k_simam_t(
    T* __restrict__ buf, const float* __restrict__ stats, int nplanes)
{
  const int p = blockIdx.x, tid = threadIdx.x;
  T* base = buf + (size_t)p * 8192;
  const float s = stats[p], ss = stats[nplanes + p];
#pragma unroll 4
  for (int i = 0; i < 32; ++i) {
    int idx = tid + i * 256;
    float v = ld1(base + idx);
    st1(base + idx, simam_elem(v, s, ss));
  }
}

// --------------------------- CNN stage 2 (unchanged) ------------------------
template <typename ZT>
__global__ __launch_bounds__(256) void k_conv2(
    const u16* __restrict__ y1u,
    const float* __restrict__ w2a, const float* __restrict__ b2a,
    const float* __restrict__ g2a, const float* __restrict__ bb2a,
    const float* __restrict__ m2a, const float* __restrict__ v2a,
    const float* __restrict__ w2b, const float* __restrict__ b2b,
    const float* __restrict__ g2b, const float* __restrict__ bb2b,
    const float* __restrict__ m2b, const float* __restrict__ v2b,
    ZT* __restrict__ z, float* __restrict__ ps2, float* __restrict__ pss2)
{
  __shared__ float y1s[32][4][66];
  __shared__ float a2[64][4][66];
  __shared__ float sA2a[64], sT2a[64], sA2b[64], sT2b[64];
  const int tid = threadIdx.x;
  const int t0 = blockIdx.x * 2, b = blockIdx.y;
  if (tid < 64) {
    float sa = g2a[tid] * rsqrtf(v2a[tid] + EPSBN);
    sA2a[tid] = sa;
    sT2a[tid] = (b2a[tid] - m2a[tid]) * sa + bb2a[tid];
    float sb = g2b[tid] * rsqrtf(v2b[tid] + EPSBN);
    sA2b[tid] = sb;
    sT2b[tid] = (b2b[tid] - m2b[tid]) * sb + bb2b[tid];
  }
  for (int i = tid; i < 32 * 4 * 66; i += 256) {
    int c1 = i / 264;
    int rr = i - c1 * 264;
    int r = rr / 66, cc = rr - r * 66;
    int t = t0 + r - 1, dd = cc - 1;
    float v = 0.f;
    if (t >= 0 && t < 128 && dd >= 0 && dd < 64)
      v = b2f(y1u[(size_t)(b * 32 + c1) * 8192 + t * 64 + dd]);
    y1s[c1][r][cc] = v;
  }
  __syncthreads();
  const int lane = tid & 63;
  const int c2base = __builtin_amdgcn_readfirstlane((int)(tid >> 6)) * 16;
#pragma unroll 1
  for (int i = 0; i < 16; ++i) {
    const int c2 = c2base + i;
    const float* wp = w2a + c2 * 32;  // uniform
    const float scl = sA2a[c2], off = sT2a[c2];
#pragma unroll 1
    for (int r = 0; r < 4; ++r) {
      for (int cc = lane; cc < 66; cc += 64) {
        float acc = 0.f;
#pragma unroll
        for (int c1 = 0; c1 < 32; ++c1) acc += y1s[c1][r][cc] * wp[c1];
        int t = t0 + r - 1, dd = cc - 1;
        float val = 0.f;
        if (t >= 0 && t < 128 && dd >= 0 && dd < 64)
          val = fmaxf(acc * scl + off, 0.f);
        a2[c2][r][cc] = val;
      }
    }
  }
  __syncthreads();
  const int d = tid & 63;
  const int gq = __builtin_amdgcn_readfirstlane((int)(tid >> 6));
  float acc[16][2];
#pragma unroll
  for (int i = 0; i < 16; ++i) { acc[i][0] = 0.f; acc[i][1] = 0.f; }
#pragma unroll 1
  for (int c1 = 0; c1 < 64; ++c1) {
    float a00 = a2[c1][0][d], a01 = a2[c1][0][d + 1], a02 = a2[c1][0][d + 2];
    float a10 = a2[c1][1][d], a11 = a2[c1][1][d + 1], a12 = a2[c1][1][d + 2];
    float a20 = a2[c1][2][d], a21 = a2[c1][2][d + 1], a22 = a2[c1][2][d + 2];
    float a30 = a2[c1][3][d], a31 = a2[c1][3][d + 1], a32 = a2[c1][3][d + 2];
#pragma unroll
    for (int i = 0; i < 16; ++i) {
      const float* wp = w2b + (size_t)((gq * 16 + i) * 64 + c1) * 9;  // uniform
      float w0 = wp[0], w1 = wp[1], w2 = wp[2];
      float w3 = wp[3], w4 = wp[4], w5 = wp[5];
      float w6 = wp[6], w7 = wp[7], w8 = wp[8];
      acc[i][0] += a00 * w0 + a01 * w1 + a02 * w2 + a10 * w3 + a11 * w4 +
                   a12 * w5 + a20 * w6 + a21 * w7 + a22 * w8;
      acc[i][1] += a10 * w0 + a11 * w1 + a12 * w2 + a20 * w3 + a21 * w4 +
                   a22 * w5 + a30 * w6 + a31 * w7 + a32 * w8;
    }
  }
#pragma unroll
  for (int i = 0; i < 16; ++i) {
    int c2 = gq * 16 + i;
    float sc = sA2b[c2], tb = sT2b[c2];
    float v0 = fmaxf(acc[i][0] * sc + tb, 0.f);
    float v1 = fmaxf(acc[i][1] * sc + tb, 0.f);
    size_t ob = (size_t)(b * 64 + c2) * 8192 + (size_t)t0 * 64 + d;
    st1(z + ob, v0);
    st1(z + ob + 64, v1);
    float s = v0 + v1, q = v0 * v0 + v1 * v1;
#pragma unroll
    for (int off = 32; off; off >>= 1) {
      s += __shfl_down(s, off);
      q += __shfl_down(q, off);
    }
    if (lane == 0) {
      ps2[(size_t)((b * 64 + c2) << 6) + blockIdx.x] = s;
      pss2[(size_t)((b * 64 + c2) << 6) + blockIdx.x] = q;
    }
  }
}

// --------------------------- persistent LSTM -------------------------------
// grid = 256 blocks (<= #CUs => all co-resident); device-scope grid barrier.
__device__ __forceinline__ void gridbar(unsigned* cnt, unsigned target) {
  __threadfence();          // drain this thread's writes to device scope
  __syncthreads();          // whole block's writes now drained
  if (threadIdx.x == 0) {
    atomicAdd(cnt, 1u);     // device-scope by default on CDNA
    while (__hip_atomic_load(cnt, __ATOMIC_ACQUIRE, __HIP_MEMORY_SCOPE_AGENT) <
           target)
      __builtin_amdgcn_s_sleep(2);
  }
  __syncthreads();
}

// q phase: xm[b,n] = 2*sigmoid(hsrc . qW[n,:] + qb[n]) * xin[b,n]
template <typename XT>
__device__ __forceinline__ void q_phase(
    const float* __restrict__ qw, const float* __restrict__ qbias,
    const float* __restrict__ hsrc, const XT* __restrict__ xin,
    size_t xin_bstride, float* __restrict__ xm, float (*hs)[256],
    int blk, int tid)
{
  const int b0 = (blk >> 6) * 32;
  for (int i = tid; i < 32 * 256; i += 256)
    hs[i >> 8][i & 255] = hsrc[(size_t)(b0 + (i >> 8)) * 256 + (i & 255)];
  __syncthreads();
  const int n = (blk & 63) * 64 + (tid & 63), bg = tid >> 6;
  float acc[8] = {0.f, 0.f, 0.f, 0.f, 0.f, 0.f, 0.f, 0.f};
  const float* wrow = qw + (size_t)n * 256;
  for (int k = 0; k < 256; k += 4) {
    float4 w = *(const float4*)(wrow + k);
#pragma unroll
    for (int j = 0; j < 8; ++j) {
      float4 hv = *(const float4*)&hs[bg * 8 + j][k];
      acc[j] += w.x * hv.x + w.y * hv.y + w.z * hv.z + w.w * hv.w;
    }
  }
  float bias = qbias[n];
#pragma unroll
  for (int j = 0; j < 8; ++j) {
    int b = b0 + bg * 8 + j;
    float xv = ld1(xin + (size_t)b * xin_bstride + n);
    xm[(size_t)b * 4096 + n] = 2.f * sigf(acc[j] + bias) * xv;
  }
}

// r phase: hm[b,n] = 2*sigmoid(xm[b,:] . rW[n,:] + rb[n]) * src[b,n]
// 2 threads per output (K split in halves), shfl-combined.
__device__ __forceinline__ void r_phase(
    const float* __restrict__ rw, const float* __restrict__ rbias,
    const float* __restrict__ src, const float* __restrict__ xm,
    float* __restrict__ hm, int blk, int tid)
{
  const int half = tid & 1, pr = tid >> 1;
  const int n = (blk & 15) * 16 + (pr & 15);
  const int b = (blk >> 4) * 8 + (pr >> 4);
  const float* wrow = rw + (size_t)n * 4096 + half * 2048;
  const float* xrow = xm + (size_t)b * 4096 + half * 2048;
  float acc = 0.f;
#pragma unroll 4
  for (int k = 0; k < 2048; k += 8) {
    float4 w0 = *(const float4*)(wrow + k);
    float4 w1 = *(const float4*)(wrow + k + 4);
    float4 x0 = *(const float4*)(xrow + k);
    float4 x1 = *(const float4*)(xrow + k + 4);
    acc += w0.x * x0.x + w0.y * x0.y + w0.z * x0.z + w0.w * x0.w +
           w1.x * x1.x + w1.y * x1.y + w1.z * x1.z + w1.w * x1.w;
  }
  float tot = acc + __shfl_xor(acc, 1);
  if (half == 0) {
    int idx = b * 256 + n;
    hm[idx] = 2.f * sigf(tot + rbias[n]) * src[idx];
  }
}

// gates + cell update. 2 threads per (b,k) pair; each does all 4 gates over
// half the K range of wih (2048) and whh (128); shfl-combine; half 0 updates.
__device__ __forceinline__ void g_phase(
    const float* __restrict__ wih, const float* __restrict__ whh,
    const float* __restrict__ bih, const float* __restrict__ bhh,
    const float* __restrict__ xm, const float* __restrict__ hm,
    float* __restrict__ h, float* __restrict__ c, int blk, int tid)
{
  const int half = tid & 1, pr = tid >> 1;
  const int kk = (blk & 15) * 16 + (pr & 15);
  const int b = (blk >> 4) * 8 + (pr >> 4);
  float a0 = 0.f, a1 = 0.f, a2 = 0.f, a3 = 0.f;
  const float* xrow = xm + (size_t)b * 4096 + half * 2048;
  const float* w0 = wih + (size_t)kk * 4096 + half * 2048;
  const float* w1 = wih + (size_t)(kk + 256) * 4096 + half * 2048;
  const float* w2 = wih + (size_t)(kk + 512) * 4096 + half * 2048;
  const float* w3 = wih + (size_t)(kk + 768) * 4096 + half * 2048;
#pragma unroll 2
  for (int k = 0; k < 2048; k += 4) {
    float4 xv = *(const float4*)(xrow + k);
    float4 wa = *(const float4*)(w0 + k);
    float4 wb = *(const float4*)(w1 + k);
    float4 wc = *(const float4*)(w2 + k);
    float4 wd = *(const float4*)(w3 + k);
    a0 += wa.x * xv.x + wa.y * xv.y + wa.z * xv.z + wa.w * xv.w;
    a1 += wb.x * xv.x + wb.y * xv.y + wb.z * xv.z + wb.w * xv.w;
    a2 += wc.x * xv.x + wc.y * xv.y + wc.z * xv.z + wc.w * xv.w;
    a3 += wd.x * xv.x + wd.y * xv.y + wd.z * xv.z + wd.w * xv.w;
  }
  const float* hrow = hm + (size_t)b * 256 + half * 128;
  const float* v0 = whh + (size_t)kk * 256 + half * 128;
  const float* v1 = whh + (size_t)(kk + 256) * 256 + half * 128;
  const float* v2 = whh + (size_t)(kk + 512) * 256 + half * 128;
  const float* v3 = whh + (size_t)(kk + 768) * 256 + half * 128;
#pragma unroll 4
  for (int k = 0; k < 128; k += 4) {
    float4 hv = *(const float4*)(hrow + k);
    float4 wa = *(const float4*)(v0 + k);
    float4 wb = *(const float4*)(v1 + k);
    float4 wc = *(const float4*)(v2 + k);
    float4 wd = *(const float4*)(v3 + k);
    a0 += wa.x * hv.x + wa.y * hv.y + wa.z * hv.z + wa.w * hv.w;
    a1 += wb.x * hv.x + wb.y * hv.y + wb.z * hv.z + wb.w * hv.w;
    a2 += wc.x * hv.x + wc.y * hv.y + wc.z * hv.z + wc.w * hv.w;
    a3 += wd.x * hv.x + wd.y * hv.y + wd.z * hv.z + wd.w * hv.w;
  }
  a0 += __shfl_xor(a0, 1);
  a1 += __shfl_xor(a1, 1);
  a2 += __shfl_xor(a2, 1);
  a3 += __shfl_xor(a3, 1);
  if (half == 0) {
    int idx = b * 256 + kk;
    float gi = a0 + bih[kk] + bhh[kk];
    float gf = a1 + bih[kk + 256] + bhh[kk + 256];
    float gg = a2 + bih[kk + 512] + bhh[kk + 512];
    float go = a3 + bih[kk + 768] + bhh[kk + 768];
    float cn = sigf(gf) * c[idx] + sigf(gi) * tanhf(gg);
    c[idx] = cn;
    h[idx] = sigf(go) * tanhf(cn);
  }
}

template <typename ZT>
__global__ __launch_bounds__(256, 1) void k_lstm(
    const ZT* __restrict__ z,
    const float* __restrict__ q0w, const float* __restrict__ q0b,
    const float* __restrict__ r0w, const float* __restrict__ r0b,
    const float* __restrict__ q1w, const float* __restrict__ q1b,
    const float* __restrict__ r1w, const float* __restrict__ r1b,
    const float* __restrict__ q2w, const float* __restrict__ q2b,
    const float* __restrict__ r2w, const float* __restrict__ r2b,
    const float* __restrict__ wih, const float* __restrict__ whh,
    const float* __restrict__ bih, const float* __restrict__ bhh,
    const float* __restrict__ fcw, const float* __restrict__ fcb,
    float* __restrict__ xm, float* __restrict__ h, float* __restrict__ c,
    float* __restrict__ hm, unsigned* __restrict__ cnt,
    float* __restrict__ out)
{
  __shared__ float hs[32][256];
  const int blk = blockIdx.x, tid = threadIdx.x;
  unsigned ep = 0;
#pragma unroll 1
  for (int t = 0; t < 128; ++t) {
    // mogrifier round 0 (x-src = z slice, h-src = h)
    q_phase<ZT>(q0w, q0b, h, z + (size_t)t * 4096, 524288, xm, hs, blk, tid);
    gridbar(cnt, (++ep) * 256);
    r_phase(r0w, r0b, h, xm, hm, blk, tid);
    gridbar(cnt, (++ep) * 256);
    // round 1
    q_phase<float>(q1w, q1b, hm, xm, 4096, xm, hs, blk, tid);
    gridbar(cnt, (++ep) * 256);
    r_phase(r1w, r1b, hm, xm, hm, blk, tid);
    gridbar(cnt, (++ep) * 256);
    // round 2
    q_phase<float>(q2w, q2b, hm, xm, 4096, xm, hs, blk, tid);
    gridbar(cnt, (++ep) * 256);
    r_phase(r2w, r2b, hm, xm, hm, blk, tid);
    gridbar(cnt, (++ep) * 256);
    // gates + cell update
    g_phase(wih, whh, bih, bhh, xm, hm, h, c, blk, tid);
    gridbar(cnt, (++ep) * 256);
  }
  // final FC: out[b,j] = h[b,:] . fcw[j,:] + fcb[j]
  if (blk < 128 && tid < 5) {
    float acc = fcb[tid];
    const float* hr = h + blk * 256;
    const float* wr = fcw + tid * 256;
    for (int k = 0; k < 256; ++k) acc += hr[k] * wr[k];
    out[blk * 5 + tid] = acc;
  }
}

// diagnostic: report ws_size (MiB) through the output if workspace too small
__global__ __launch_bounds__(256) void k_report(float* out, float v, int n) {
  int i = blockIdx.x * 256 + threadIdx.x;
  if (i < n) out[i] = v;
}

// ---------------------------------------------------------------------------
struct Net {
  const float *x;
  const float *c1a_w, *c1a_b, *g1a, *b1a, *m1a, *v1a;
  const float *c1b_w, *c1b_b, *g1b, *b1b, *m1b, *v1b;
  const float *c2a_w, *c2a_b, *g2a, *b2a, *m2a, *v2a;
  const float *c2b_w, *c2b_b, *g2b, *b2b, *m2b, *v2b;
  const float *qw[3], *qb[3], *rw[3], *rb[3];
  const float *wih, *whh, *bih, *bhh, *fcw, *fcb;
};

template <typename ZT>
static void run_all(const Net& p, ZT* z, u16* y1u, float* scr,
                    float* ps1, float* pss1, float* st1v,
                    float* ps2, float* pss2, float* st2v,
                    float* out, hipStream_t stream)
{
  float* xm = scr;            // 524,288 floats
  float* h  = scr + 524288;   // 32,768
  float* c  = scr + 557056;   // 32,768
  float* hm = scr + 589824;   // 32,768
  unsigned* cnt = (unsigned*)(scr + 622592);

  k_conv1<<<dim3(128, 32), 256, 0, stream>>>(p.x, p.c1a_w, p.c1a_b, p.g1a,
      p.b1a, p.m1a, p.v1a, p.c1b_w, p.c1b_b, p.g1b, p.b1b, p.m1b, p.v1b,
      y1u, ps1, pss1);
  k_red<<<16, 256, 0, stream>>>(ps1, pss1, st1v, 32, 4096);
  k_simam_t<u16><<<4096, 256, 0, stream>>>(y1u, st1v, 4096);
  k_conv2<ZT><<<dim3(64, 128), 256, 0, stream>>>(y1u, p.c2a_w, p.c2a_b, p.g2a,
      p.b2a, p.m2a, p.v2a, p.c2b_w, p.c2b_b, p.g2b, p.b2b, p.m2b, p.v2b,
      z, ps2, pss2);
  k_red<<<32, 256, 0, stream>>>(ps2, pss2, st2v, 64, 8192);
  k_simam_t<ZT><<<8192, 256, 0, stream>>>(z, st2v, 8192);

  // zero h, c (contiguous) and the barrier counter; scr overlays y1u, which
  // is dead after k_conv2 above (stream-ordered).
  hipMemsetAsync(h, 0, 2 * 32768 * sizeof(float), stream);
  hipMemsetAsync(cnt, 0, sizeof(unsigned), stream);

  k_lstm<ZT><<<256, 256, 0, stream>>>(z,
      p.qw[0], p.qb[0], p.rw[0], p.rb[0],
      p.qw[1], p.qb[1], p.rw[1], p.rb[1],
      p.qw[2], p.qb[2], p.rw[2], p.rb[2],
      p.wih, p.whh, p.bih, p.bhh, p.fcw, p.fcb,
      xm, h, c, hm, cnt, out);
}

extern "C" void kernel_launch(void* const* d_in, const int* in_sizes, int n_in,
                              void* d_out, int out_size, void* d_ws, size_t ws_size,
                              hipStream_t stream)
{
  (void)in_sizes; (void)n_in;
  Net p;
  p.x = (const float*)d_in[0];
  p.c1a_w = (const float*)d_in[1];  p.c1a_b = (const float*)d_in[2];
  p.g1a = (const float*)d_in[3];    p.b1a = (const float*)d_in[4];
  p.m1a = (const float*)d_in[5];    p.v1a = (const float*)d_in[6];
  p.c1b_w = (const float*)d_in[7];  p.c1b_b = (const float*)d_in[8];
  p.g1b = (const float*)d_in[9];    p.b1b = (const float*)d_in[10];
  p.m1b = (const float*)d_in[11];   p.v1b = (const float*)d_in[12];
  p.c2a_w = (const float*)d_in[13]; p.c2a_b = (const float*)d_in[14];
  p.g2a = (const float*)d_in[15];   p.b2a = (const float*)d_in[16];
  p.m2a = (const float*)d_in[17];   p.v2a = (const float*)d_in[18];
  p.c2b_w = (const float*)d_in[19]; p.c2b_b = (const float*)d_in[20];
  p.g2b = (const float*)d_in[21];   p.b2b = (const float*)d_in[22];
  p.m2b = (const float*)d_in[23];   p.v2b = (const float*)d_in[24];
  for (int i = 0; i < 3; ++i) {
    p.qw[i] = (const float*)d_in[25 + 4 * i];
    p.qb[i] = (const float*)d_in[26 + 4 * i];
    p.rw[i] = (const float*)d_in[27 + 4 * i];
    p.rb[i] = (const float*)d_in[28 + 4 * i];
  }
  p.wih = (const float*)d_in[37]; p.whh = (const float*)d_in[38];
  p.bih = (const float*)d_in[39]; p.bhh = (const float*)d_in[40];
  p.fcw = (const float*)d_in[41]; p.fcb = (const float*)d_in[42];
  float* out = (float*)d_out;
  char* base = (char*)d_ws;

  const size_t ZB_F32 = 268435456, ZB_BF16 = 134217728, Y1B = 67108864;
  const size_t STATS = 1048576 * 2 + 65536 + 2097152 * 2 + 65536;
  const size_t HI_NEED = ZB_F32 + Y1B + STATS;   // ~326 MiB
  const size_t LO_NEED = ZB_BF16 + Y1B + STATS;  // ~198 MiB

  if (ws_size >= HI_NEED) {
    float* z = (float*)base;
    u16* y1u = (u16*)(base + ZB_F32);
    float* scr = (float*)(base + ZB_F32);  // overlays y1u after conv2 is done
    char* sb = base + ZB_F32 + Y1B;
    run_all<float>(p, z, y1u, scr,
                   (float*)sb, (float*)(sb + 1048576), (float*)(sb + 2097152),
                   (float*)(sb + 2162688), (float*)(sb + 4259840),
                   (float*)(sb + 6356992), out, stream);
  } else if (ws_size >= LO_NEED) {
    u16* z = (u16*)base;
    u16* y1u = (u16*)(base + ZB_BF16);
    float* scr = (float*)(base + ZB_BF16);  // overlays y1u after conv2 is done
    char* sb = base + ZB_BF16 + Y1B;
    run_all<u16>(p, z, y1u, scr,
                 (float*)sb, (float*)(sb + 1048576), (float*)(sb + 2097152),
                 (float*)(sb + 2162688), (float*)(sb + 4259840),
                 (float*)(sb + 6356992), out, stream);
  } else {
    k_report<<<3, 256, 0, stream>>>(out, (float)(ws_size >> 20), out_size);
  }
}

// Round 4
// 80650.800 us; speedup vs baseline: 1.3639x; 1.3639x over previous
//
#include <hip/hip_runtime.h>
#include <math.h>

// ---------------------------------------------------------------------------
// SimAM-CNN + Mogrifier-LSTM (Round 4): persistent LSTM with register-tiled
// phases (8-batch weight reuse per thread), wave-K-split + shuffle/LDS
// reduction, 4-counter grid barrier. CNN unchanged (R2-verified).
// xl[b,t,:] = z + b*524288 + t*4096 (flat NCHW reinterpret).
// ---------------------------------------------------------------------------

typedef unsigned short u16;

#define EPSBN 1e-5f

__device__ __forceinline__ float sigf(float x) { return 1.0f / (1.0f + expf(-x)); }

__device__ __forceinline__ float b2f(u16 u) {
  union { unsigned int i; float f; } v; v.i = ((unsigned int)u) << 16; return v.f;
}
__device__ __forceinline__ u16 f2b(float f) {
  union { float f; unsigned int i; } v; v.f = f;
  unsigned int r = v.i + 0x7FFFu + ((v.i >> 16) & 1u);
  return (u16)(r >> 16);
}

template <typename T> __device__ __forceinline__ float ld1(const T* p);
template <> __device__ __forceinline__ float ld1<float>(const float* p) { return *p; }
template <> __device__ __forceinline__ float ld1<u16>(const u16* p) { return b2f(*p); }
template <typename T> __device__ __forceinline__ void st1(T* p, float v);
template <> __device__ __forceinline__ void st1<float>(float* p, float v) { *p = v; }
template <> __device__ __forceinline__ void st1<u16>(u16* p, float v) { *p = f2b(v); }

template <typename T> __device__ __forceinline__ float4 ld4v(const T* p);
template <> __device__ __forceinline__ float4 ld4v<float>(const float* p) {
  return *(const float4*)p;
}
template <> __device__ __forceinline__ float4 ld4v<u16>(const u16* p) {
  ushort4 u = *(const ushort4*)p;
  return make_float4(b2f(u.x), b2f(u.y), b2f(u.z), b2f(u.w));
}

__device__ __forceinline__ float simam_elem(float xv, float s, float ss) {
  float mu = (s - xv) * (1.0f / 8191.0f);
  float var = (ss - xv * xv - 8191.0f * mu * mu) * (1.0f / 8190.0f);
  float einv = ((xv - mu) * (xv - mu) + 2.0f * var + 0.2f) / (4.0f * (var + 0.1f));
  return xv * sigf(einv);
}

// --------------------------- CNN stage 1 (R2-verified) ----------------------
__global__ __launch_bounds__(256) void k_conv1(
    const float* __restrict__ x,
    const float* __restrict__ w1a, const float* __restrict__ b1a,
    const float* __restrict__ g1a, const float* __restrict__ bb1a,
    const float* __restrict__ m1a, const float* __restrict__ v1a,
    const float* __restrict__ w1b, const float* __restrict__ b1b,
    const float* __restrict__ g1b, const float* __restrict__ bb1b,
    const float* __restrict__ m1b, const float* __restrict__ v1b,
    u16* __restrict__ y1u, float* __restrict__ ps1, float* __restrict__ pss1)
{
  __shared__ float xs[6][66];
  __shared__ float a1[32][6][66];
  __shared__ float A1[32], T1[32], S2[32], T2[32];
  __shared__ float reds[4][32], redq[4][32];
  const int tid = threadIdx.x;
  const int b = blockIdx.x, t0 = blockIdx.y * 4;
  if (tid < 32) {
    float s = g1a[tid] * rsqrtf(v1a[tid] + EPSBN);
    A1[tid] = w1a[tid] * s;
    T1[tid] = (b1a[tid] - m1a[tid]) * s + bb1a[tid];
    float s2 = g1b[tid] * rsqrtf(v1b[tid] + EPSBN);
    S2[tid] = s2;
    T2[tid] = (b1b[tid] - m1b[tid]) * s2 + bb1b[tid];
  }
  for (int i = tid; i < 6 * 66; i += 256) {
    int r = i / 66, cc = i - r * 66;
    int t = t0 + r - 1, d = cc - 1;
    float v = 0.f;
    if (t >= 0 && t < 128 && d >= 0 && d < 64) v = x[(b * 128 + t) * 64 + d];
    xs[r][cc] = v;
  }
  __syncthreads();
  for (int i = tid; i < 32 * 6 * 66; i += 256) {
    int c = i / 396;
    int rr = i - c * 396;
    int r = rr / 66, cc = rr - r * 66;
    int t = t0 + r - 1, d = cc - 1;
    float v = 0.f;
    if (t >= 0 && t < 128 && d >= 0 && d < 64)
      v = fmaxf(xs[r][cc] * A1[c] + T1[c], 0.f);
    a1[c][r][cc] = v;
  }
  __syncthreads();
  const int d = tid & 63, tq = tid >> 6, lane = tid & 63;
  float acc[32];
#pragma unroll
  for (int i = 0; i < 32; ++i) acc[i] = 0.f;
#pragma unroll 1
  for (int c1 = 0; c1 < 32; ++c1) {
#pragma unroll
    for (int dt = 0; dt < 3; ++dt) {
      float av0 = a1[c1][tq + dt][d];
      float av1 = a1[c1][tq + dt][d + 1];
      float av2 = a1[c1][tq + dt][d + 2];
#pragma unroll
      for (int c2 = 0; c2 < 32; ++c2) {
        const float* wp = w1b + ((c2 * 32 + c1) * 3 + dt) * 3;  // uniform
        acc[c2] += av0 * wp[0] + av1 * wp[1] + av2 * wp[2];
      }
    }
  }
  const size_t ob = (size_t)b * 32 * 8192 + (size_t)(t0 + tq) * 64 + d;
#pragma unroll
  for (int c2 = 0; c2 < 32; ++c2) {
    float v = fmaxf(acc[c2] * S2[c2] + T2[c2], 0.f);
    y1u[ob + (size_t)c2 * 8192] = f2b(v);
    float s = v, q = v * v;
#pragma unroll
    for (int off = 32; off; off >>= 1) {
      s += __shfl_down(s, off);
      q += __shfl_down(q, off);
    }
    if (lane == 0) { reds[tq][c2] = s; redq[tq][c2] = q; }
  }
  __syncthreads();
  if (tid < 32) {
    float s = (reds[0][tid] + reds[1][tid]) + (reds[2][tid] + reds[3][tid]);
    float q = (redq[0][tid] + redq[1][tid]) + (redq[2][tid] + redq[3][tid]);
    ps1[(size_t)((b * 32 + tid) << 5) + blockIdx.y] = s;
    pss1[(size_t)((b * 32 + tid) << 5) + blockIdx.y] = q;
  }
}

__global__ __launch_bounds__(256) void k_red(
    const float* __restrict__ ps, const float* __restrict__ pss,
    float* __restrict__ stats, int npart, int nplanes)
{
  int p = blockIdx.x * 256 + threadIdx.x;
  if (p >= nplanes) return;
  float s = 0.f, q = 0.f;
  for (int j = 0; j < npart; ++j) {
    s += ps[(size_t)p * npart + j];
    q += pss[(size_t)p * npart + j];
  }
  stats[p] = s;
  stats[nplanes + p] = q;
}

template <typename T>
__global__ __launch_bounds__(256) void k_simam_t(
    T* __restrict__ buf, const float* __restrict__ stats, int nplanes)
{
  const int p = blockIdx.x, tid = threadIdx.x;
  T* base = buf + (size_t)p * 8192;
  const float s = stats[p], ss = stats[nplanes + p];
#pragma unroll 4
  for (int i = 0; i < 32; ++i) {
    int idx = tid + i * 256;
    float v = ld1(base + idx);
    st1(base + idx, simam_elem(v, s, ss));
  }
}

// --------------------------- CNN stage 2 (R2-verified) ----------------------
template <typename ZT>
__global__ __launch_bounds__(256) void k_conv2(
    const u16* __restrict__ y1u,
    const float* __restrict__ w2a, const float* __restrict__ b2a,
    const float* __restrict__ g2a, const float* __restrict__ bb2a,
    const float* __restrict__ m2a, const float* __restrict__ v2a,
    const float* __restrict__ w2b, const float* __restrict__ b2b,
    const float* __restrict__ g2b, const float* __restrict__ bb2b,
    const float* __restrict__ m2b, const float* __restrict__ v2b,
    ZT* __restrict__ z, float* __restrict__ ps2, float* __restrict__ pss2)
{
  __shared__ float y1s[32][4][66];
  __shared__ float a2[64][4][66];
  __shared__ float sA2a[64], sT2a[64], sA2b[64], sT2b[64];
  const int tid = threadIdx.x;
  const int t0 = blockIdx.x * 2, b = blockIdx.y;
  if (tid < 64) {
    float sa = g2a[tid] * rsqrtf(v2a[tid] + EPSBN);
    sA2a[tid] = sa;
    sT2a[tid] = (b2a[tid] - m2a[tid]) * sa + bb2a[tid];
    float sb = g2b[tid] * rsqrtf(v2b[tid] + EPSBN);
    sA2b[tid] = sb;
    sT2b[tid] = (b2b[tid] - m2b[tid]) * sb + bb2b[tid];
  }
  for (int i = tid; i < 32 * 4 * 66; i += 256) {
    int c1 = i / 264;
    int rr = i - c1 * 264;
    int r = rr / 66, cc = rr - r * 66;
    int t = t0 + r - 1, dd = cc - 1;
    float v = 0.f;
    if (t >= 0 && t < 128 && dd >= 0 && dd < 64)
      v = b2f(y1u[(size_t)(b * 32 + c1) * 8192 + t * 64 + dd]);
    y1s[c1][r][cc] = v;
  }
  __syncthreads();
  const int lane = tid & 63;
  const int c2base = __builtin_amdgcn_readfirstlane((int)(tid >> 6)) * 16;
#pragma unroll 1
  for (int i = 0; i < 16; ++i) {
    const int c2 = c2base + i;
    const float* wp = w2a + c2 * 32;  // uniform
    const float scl = sA2a[c2], off = sT2a[c2];
#pragma unroll 1
    for (int r = 0; r < 4; ++r) {
      for (int cc = lane; cc < 66; cc += 64) {
        float acc = 0.f;
#pragma unroll
        for (int c1 = 0; c1 < 32; ++c1) acc += y1s[c1][r][cc] * wp[c1];
        int t = t0 + r - 1, dd = cc - 1;
        float val = 0.f;
        if (t >= 0 && t < 128 && dd >= 0 && dd < 64)
          val = fmaxf(acc * scl + off, 0.f);
        a2[c2][r][cc] = val;
      }
    }
  }
  __syncthreads();
  const int d = tid & 63;
  const int gq = __builtin_amdgcn_readfirstlane((int)(tid >> 6));
  float acc[16][2];
#pragma unroll
  for (int i = 0; i < 16; ++i) { acc[i][0] = 0.f; acc[i][1] = 0.f; }
#pragma unroll 1
  for (int c1 = 0; c1 < 64; ++c1) {
    float a00 = a2[c1][0][d], a01 = a2[c1][0][d + 1], a02 = a2[c1][0][d + 2];
    float a10 = a2[c1][1][d], a11 = a2[c1][1][d + 1], a12 = a2[c1][1][d + 2];
    float a20 = a2[c1][2][d], a21 = a2[c1][2][d + 1], a22 = a2[c1][2][d + 2];
    float a30 = a2[c1][3][d], a31 = a2[c1][3][d + 1], a32 = a2[c1][3][d + 2];
#pragma unroll
    for (int i = 0; i < 16; ++i) {
      const float* wp = w2b + (size_t)((gq * 16 + i) * 64 + c1) * 9;  // uniform
      float w0 = wp[0], w1 = wp[1], w2 = wp[2];
      float w3 = wp[3], w4 = wp[4], w5 = wp[5];
      float w6 = wp[6], w7 = wp[7], w8 = wp[8];
      acc[i][0] += a00 * w0 + a01 * w1 + a02 * w2 + a10 * w3 + a11 * w4 +
                   a12 * w5 + a20 * w6 + a21 * w7 + a22 * w8;
      acc[i][1] += a10 * w0 + a11 * w1 + a12 * w2 + a20 * w3 + a21 * w4 +
                   a22 * w5 + a30 * w6 + a31 * w7 + a32 * w8;
    }
  }
#pragma unroll
  for (int i = 0; i < 16; ++i) {
    int c2 = gq * 16 + i;
    float sc = sA2b[c2], tb = sT2b[c2];
    float v0 = fmaxf(acc[i][0] * sc + tb, 0.f);
    float v1 = fmaxf(acc[i][1] * sc + tb, 0.f);
    size_t ob = (size_t)(b * 64 + c2) * 8192 + (size_t)t0 * 64 + d;
    st1(z + ob, v0);
    st1(z + ob + 64, v1);
    float s = v0 + v1, q = v0 * v0 + v1 * v1;
#pragma unroll
    for (int off = 32; off; off >>= 1) {
      s += __shfl_down(s, off);
      q += __shfl_down(q, off);
    }
    if (lane == 0) {
      ps2[(size_t)((b * 64 + c2) << 6) + blockIdx.x] = s;
      pss2[(size_t)((b * 64 + c2) << 6) + blockIdx.x] = q;
    }
  }
}

// --------------------------- persistent LSTM -------------------------------
// 4 spread counters cut arrival contention ~4x vs single counter.
__device__ __forceinline__ void gridbar(unsigned* cnt, unsigned ep) {
  __threadfence();
  __syncthreads();
  if (threadIdx.x == 0) {
    atomicAdd(&cnt[(blockIdx.x & 3) * 64], 1u);
    const unsigned target = ep * 256u;
    for (;;) {
      unsigned s =
          __hip_atomic_load(&cnt[0], __ATOMIC_ACQUIRE, __HIP_MEMORY_SCOPE_AGENT) +
          __hip_atomic_load(&cnt[64], __ATOMIC_ACQUIRE, __HIP_MEMORY_SCOPE_AGENT) +
          __hip_atomic_load(&cnt[128], __ATOMIC_ACQUIRE, __HIP_MEMORY_SCOPE_AGENT) +
          __hip_atomic_load(&cnt[192], __ATOMIC_ACQUIRE, __HIP_MEMORY_SCOPE_AGENT);
      if (s >= target) break;
      __builtin_amdgcn_s_sleep(1);
    }
  }
  __syncthreads();
}

// q: xm[b,n] = 2*sigmoid(hsrc[b,:256].qw[n,:] + qb[n]) * xin[b,n]
// block tile 64n x 32b; thread 4n x 8b; lane=(ksub4, ns16), wave=bsub.
template <typename XT>
__device__ __forceinline__ void q_phase(
    const float* __restrict__ qw, const float* __restrict__ qb,
    const float* __restrict__ hsrc, const XT* __restrict__ xin,
    size_t xstride, float* __restrict__ xm, int blk, int tid)
{
  const int lane = tid & 63, w = tid >> 6;
  const int ksub = lane >> 4, ns = lane & 15;
  const int n0 = (blk & 63) * 64 + ns * 4;
  const int b0 = (blk >> 6) * 32 + w * 8;
  const int kb = ksub * 64;
  float acc[4][8];
#pragma unroll
  for (int i = 0; i < 4; ++i)
#pragma unroll
    for (int j = 0; j < 8; ++j) acc[i][j] = 0.f;
#pragma unroll 2
  for (int k = 0; k < 64; k += 4) {
    float4 wv[4];
#pragma unroll
    for (int i = 0; i < 4; ++i)
      wv[i] = *(const float4*)(qw + (size_t)(n0 + i) * 256 + kb + k);
#pragma unroll
    for (int j = 0; j < 8; ++j) {
      float4 hv = *(const float4*)(hsrc + (size_t)(b0 + j) * 256 + kb + k);
#pragma unroll
      for (int i = 0; i < 4; ++i)
        acc[i][j] += wv[i].x * hv.x + wv[i].y * hv.y + wv[i].z * hv.z +
                     wv[i].w * hv.w;
    }
  }
#pragma unroll
  for (int i = 0; i < 4; ++i)
#pragma unroll
    for (int j = 0; j < 8; ++j) {
      acc[i][j] += __shfl_xor(acc[i][j], 16);
      acc[i][j] += __shfl_xor(acc[i][j], 32);
    }
  if (ksub == 0) {
    float bq0 = qb[n0], bq1 = qb[n0 + 1], bq2 = qb[n0 + 2], bq3 = qb[n0 + 3];
#pragma unroll
    for (int j = 0; j < 8; ++j) {
      float4 xv = ld4v(xin + (size_t)(b0 + j) * xstride + n0);
      float4 o;
      o.x = 2.f * sigf(acc[0][j] + bq0) * xv.x;
      o.y = 2.f * sigf(acc[1][j] + bq1) * xv.y;
      o.z = 2.f * sigf(acc[2][j] + bq2) * xv.z;
      o.w = 2.f * sigf(acc[3][j] + bq3) * xv.w;
      *(float4*)(xm + (size_t)(b0 + j) * 4096 + n0) = o;
    }
  }
}

// r: hm[b,n] = 2*sigmoid(xm[b,:4096].rw[n,:] + rb[n]) * src[b,n]
// block tile 16n x 8b; thread 4n x 8b over K=64 (64-lane K-split); LDS reduce.
__device__ __forceinline__ void r_phase(
    const float* __restrict__ rw, const float* __restrict__ rb,
    const float* __restrict__ src, const float* __restrict__ xm,
    float* __restrict__ hm, float* __restrict__ red, int blk, int tid)
{
  const int lane = tid & 63, w = tid >> 6;
  const int n0 = (blk & 15) * 16 + w * 4;
  const int b0 = (blk >> 4) * 8;
  const int kb = lane * 64;
  float acc[4][8];
#pragma unroll
  for (int i = 0; i < 4; ++i)
#pragma unroll
    for (int j = 0; j < 8; ++j) acc[i][j] = 0.f;
#pragma unroll 2
  for (int k = 0; k < 64; k += 4) {
    float4 wv[4];
#pragma unroll
    for (int i = 0; i < 4; ++i)
      wv[i] = *(const float4*)(rw + (size_t)(n0 + i) * 4096 + kb + k);
#pragma unroll
    for (int j = 0; j < 8; ++j) {
      float4 xv = *(const float4*)(xm + (size_t)(b0 + j) * 4096 + kb + k);
#pragma unroll
      for (int i = 0; i < 4; ++i)
        acc[i][j] += wv[i].x * xv.x + wv[i].y * xv.y + wv[i].z * xv.z +
                     wv[i].w * xv.w;
    }
  }
  // LDS reduction over the 64-lane K-split: red[(w*64+L)*33 + m]
  float* myred = red + (size_t)tid * 33;
#pragma unroll
  for (int m = 0; m < 32; ++m) myred[m] = acc[m >> 3][m & 7];
  __syncthreads();
  if (lane < 32) {
    const float* rbase = red + (size_t)w * 64 * 33;
    float s = 0.f;
#pragma unroll 8
    for (int L = 0; L < 64; ++L) s += rbase[L * 33 + lane];
    int i = lane >> 3, j = lane & 7;
    int n = n0 + i;
    int idx = (b0 + j) * 256 + n;
    hm[idx] = 2.f * sigf(s + rb[n]) * src[idx];
  }
}

// gates partials: block tile 64 rows x 64b, K-chunk 512 (8 ks blocks);
// thread 8n x 8b, 4-way lane K-split + shfl reduce. ks==0 blocks also do whh.
__device__ __forceinline__ void g_phase(
    const float* __restrict__ wih, const float* __restrict__ whh,
    const float* __restrict__ xm, const float* __restrict__ hm,
    float* __restrict__ gslab, float* __restrict__ xsm, int blk, int tid)
{
  const int lane = tid & 63, w = tid >> 6;
  const int ksub = lane >> 4;
  const int slot = w * 16 + (lane & 15);
  const int nsub = slot & 7, bsub = slot >> 3;
  const int nt = blk & 15, bg = (blk >> 4) & 1, ks = blk >> 5;
  const int n0 = nt * 64 + nsub * 8;
  const int b0 = bg * 64 + bsub * 8;
  float acc[8][8];
#pragma unroll
  for (int i = 0; i < 8; ++i)
#pragma unroll
    for (int j = 0; j < 8; ++j) acc[i][j] = 0.f;
  const int srow = tid >> 2, spart = tid & 3;
#pragma unroll 1
  for (int chunk = 0; chunk < 2; ++chunk) {
    const int kc = ks * 512 + chunk * 256;
    __syncthreads();
    {
      const float* s = xm + (size_t)(bg * 64 + srow) * 4096 + kc + spart * 64;
      float* d = xsm + srow * 260 + spart * 64;
#pragma unroll
      for (int i = 0; i < 64; i += 4) *(float4*)(d + i) = *(const float4*)(s + i);
    }
    __syncthreads();
    const int kb = ksub * 64;
#pragma unroll 2
    for (int k = 0; k < 64; k += 4) {
      float4 wv[8];
#pragma unroll
      for (int i = 0; i < 8; ++i)
        wv[i] = *(const float4*)(wih + (size_t)(n0 + i) * 4096 + kc + kb + k);
#pragma unroll
      for (int j = 0; j < 8; ++j) {
        float4 xv = *(const float4*)(xsm + (bsub * 8 + j) * 260 + kb + k);
#pragma unroll
        for (int i = 0; i < 8; ++i)
          acc[i][j] += wv[i].x * xv.x + wv[i].y * xv.y + wv[i].z * xv.z +
                       wv[i].w * xv.w;
      }
    }
  }
#pragma unroll
  for (int i = 0; i < 8; ++i)
#pragma unroll
    for (int j = 0; j < 8; ++j) {
      acc[i][j] += __shfl_xor(acc[i][j], 16);
      acc[i][j] += __shfl_xor(acc[i][j], 32);
    }
  if (ksub == 0) {
    float* gs = gslab + (size_t)ks * 131072;
#pragma unroll
    for (int j = 0; j < 8; ++j) {
      float4 o1 = make_float4(acc[0][j], acc[1][j], acc[2][j], acc[3][j]);
      float4 o2 = make_float4(acc[4][j], acc[5][j], acc[6][j], acc[7][j]);
      float* p = gs + (size_t)(b0 + j) * 1024 + n0;
      *(float4*)p = o1;
      *(float4*)(p + 4) = o2;
    }
  }
  if (ks == 0) {
    // whh contribution -> slab 8 (rows n0.., K=256 over hm)
    __syncthreads();
    {
      const float* s = hm + (size_t)(bg * 64 + srow) * 256 + spart * 64;
      float* d = xsm + srow * 260 + spart * 64;
#pragma unroll
      for (int i = 0; i < 64; i += 4) *(float4*)(d + i) = *(const float4*)(s + i);
    }
    __syncthreads();
    float a2[8][8];
#pragma unroll
    for (int i = 0; i < 8; ++i)
#pragma unroll
      for (int j = 0; j < 8; ++j) a2[i][j] = 0.f;
    const int kb = ksub * 64;
#pragma unroll 2
    for (int k = 0; k < 64; k += 4) {
      float4 wv[8];
#pragma unroll
      for (int i = 0; i < 8; ++i)
        wv[i] = *(const float4*)(whh + (size_t)(n0 + i) * 256 + kb + k);
#pragma unroll
      for (int j = 0; j < 8; ++j) {
        float4 xv = *(const float4*)(xsm + (bsub * 8 + j) * 260 + kb + k);
#pragma unroll
        for (int i = 0; i < 8; ++i)
          a2[i][j] += wv[i].x * xv.x + wv[i].y * xv.y + wv[i].z * xv.z +
                      wv[i].w * xv.w;
      }
    }
#pragma unroll
    for (int i = 0; i < 8; ++i)
#pragma unroll
      for (int j = 0; j < 8; ++j) {
        a2[i][j] += __shfl_xor(a2[i][j], 16);
        a2[i][j] += __shfl_xor(a2[i][j], 32);
      }
    if (ksub == 0) {
      float* gs = gslab + (size_t)8 * 131072;
#pragma unroll
      for (int j = 0; j < 8; ++j) {
        float4 o1 = make_float4(a2[0][j], a2[1][j], a2[2][j], a2[3][j]);
        float4 o2 = make_float4(a2[4][j], a2[5][j], a2[6][j], a2[7][j]);
        float* p = gs + (size_t)(b0 + j) * 1024 + n0;
        *(float4*)p = o1;
        *(float4*)(p + 4) = o2;
      }
    }
  }
}

// finalize gates -> h, c  (9 slabs: 8 wih K-chunks + whh)
__device__ __forceinline__ void hfin_phase(
    const float* __restrict__ gslab, const float* __restrict__ bih,
    const float* __restrict__ bhh, float* __restrict__ h,
    float* __restrict__ c, int blk, int tid)
{
  int i = blk * 256 + tid;
  if (i >= 32768) return;
  int b = i >> 8, kk = i & 255;
  float gi = bih[kk] + bhh[kk];
  float gf = bih[kk + 256] + bhh[kk + 256];
  float gg = bih[kk + 512] + bhh[kk + 512];
  float go = bih[kk + 768] + bhh[kk + 768];
#pragma unroll
  for (int s = 0; s < 9; ++s) {
    const float* gs = gslab + (size_t)s * 131072 + b * 1024 + kk;
    gi += gs[0]; gf += gs[256]; gg += gs[512]; go += gs[768];
  }
  float cn = sigf(gf) * c[i] + sigf(gi) * tanhf(gg);
  c[i] = cn;
  h[i] = sigf(go) * tanhf(cn);
}

template <typename ZT>
__global__ __launch_bounds__(256, 1) void k_lstm(
    const ZT* __restrict__ z,
    const float* __restrict__ q0w, const float* __restrict__ q0b,
    const float* __restrict__ r0w, const float* __restrict__ r0b,
    const float* __restrict__ q1w, const float* __restrict__ q1b,
    const float* __restrict__ r1w, const float* __restrict__ r1b,
    const float* __restrict__ q2w, const float* __restrict__ q2b,
    const float* __restrict__ r2w, const float* __restrict__ r2b,
    const float* __restrict__ wih, const float* __restrict__ whh,
    const float* __restrict__ bih, const float* __restrict__ bhh,
    const float* __restrict__ fcw, const float* __restrict__ fcb,
    float* __restrict__ xm, float* __restrict__ h, float* __restrict__ c,
    float* __restrict__ hm, float* __restrict__ gslab,
    unsigned* __restrict__ cnt, float* __restrict__ out)
{
  __shared__ float smem[64 * 260];  // g staging (66.5KB) / r reduce (33.8KB)
  const int blk = blockIdx.x, tid = threadIdx.x;
  unsigned ep = 0;
#pragma unroll 1
  for (int t = 0; t < 128; ++t) {
    q_phase<ZT>(q0w, q0b, h, z + (size_t)t * 4096, 524288, xm, blk, tid);
    gridbar(cnt, ++ep);
    r_phase(r0w, r0b, h, xm, hm, smem, blk, tid);
    gridbar(cnt, ++ep);
    q_phase<float>(q1w, q1b, hm, xm, 4096, xm, blk, tid);
    gridbar(cnt, ++ep);
    r_phase(r1w, r1b, hm, xm, hm, smem, blk, tid);
    gridbar(cnt, ++ep);
    q_phase<float>(q2w, q2b, hm, xm, 4096, xm, blk, tid);
    gridbar(cnt, ++ep);
    r_phase(r2w, r2b, hm, xm, hm, smem, blk, tid);
    gridbar(cnt, ++ep);
    g_phase(wih, whh, xm, hm, gslab, smem, blk, tid);
    gridbar(cnt, ++ep);
    hfin_phase(gslab, bih, bhh, h, c, blk, tid);
    gridbar(cnt, ++ep);
  }
  if (blk < 128 && tid < 5) {
    float acc = fcb[tid];
    const float* hr = h + blk * 256;
    const float* wr = fcw + tid * 256;
    for (int k = 0; k < 256; ++k) acc += hr[k] * wr[k];
    out[blk * 5 + tid] = acc;
  }
}

__global__ __launch_bounds__(256) void k_report(float* out, float v, int n) {
  int i = blockIdx.x * 256 + threadIdx.x;
  if (i < n) out[i] = v;
}

// ---------------------------------------------------------------------------
struct Net {
  const float *x;
  const float *c1a_w, *c1a_b, *g1a, *b1a, *m1a, *v1a;
  const float *c1b_w, *c1b_b, *g1b, *b1b, *m1b, *v1b;
  const float *c2a_w, *c2a_b, *g2a, *b2a, *m2a, *v2a;
  const float *c2b_w, *c2b_b, *g2b, *b2b, *m2b, *v2b;
  const float *qw[3], *qb[3], *rw[3], *rb[3];
  const float *wih, *whh, *bih, *bhh, *fcw, *fcb;
};

template <typename ZT>
static void run_all(const Net& p, ZT* z, u16* y1u, float* scr,
                    float* ps1, float* pss1, float* st1v,
                    float* ps2, float* pss2, float* st2v,
                    float* out, hipStream_t stream)
{
  float* xm    = scr;             // 524,288 floats
  float* h     = scr + 524288;    // 32,768
  float* c     = scr + 557056;    // 32,768
  float* hm    = scr + 589824;    // 32,768
  float* gslab = scr + 622592;    // 9 * 131,072 = 1,179,648
  unsigned* cnt = (unsigned*)(scr + 1802240);  // 4 counters, 256B apart

  k_conv1<<<dim3(128, 32), 256, 0, stream>>>(p.x, p.c1a_w, p.c1a_b, p.g1a,
      p.b1a, p.m1a, p.v1a, p.c1b_w, p.c1b_b, p.g1b, p.b1b, p.m1b, p.v1b,
      y1u, ps1, pss1);
  k_red<<<16, 256, 0, stream>>>(ps1, pss1, st1v, 32, 4096);
  k_simam_t<u16><<<4096, 256, 0, stream>>>(y1u, st1v, 4096);
  k_conv2<ZT><<<dim3(64, 128), 256, 0, stream>>>(y1u, p.c2a_w, p.c2a_b, p.g2a,
      p.b2a, p.m2a, p.v2a, p.c2b_w, p.c2b_b, p.g2b, p.b2b, p.m2b, p.v2b,
      z, ps2, pss2);
  k_red<<<32, 256, 0, stream>>>(ps2, pss2, st2v, 64, 8192);
  k_simam_t<ZT><<<8192, 256, 0, stream>>>(z, st2v, 8192);

  hipMemsetAsync(h, 0, 2 * 32768 * sizeof(float), stream);  // h and c
  hipMemsetAsync(cnt, 0, 1024, stream);                     // barrier counters

  k_lstm<ZT><<<256, 256, 0, stream>>>(z,
      p.qw[0], p.qb[0], p.rw[0], p.rb[0],
      p.qw[1], p.qb[1], p.rw[1], p.rb[1],
      p.qw[2], p.qb[2], p.rw[2], p.rb[2],
      p.wih, p.whh, p.bih, p.bhh, p.fcw, p.fcb,
      xm, h, c, hm, gslab, cnt, out);
}

extern "C" void kernel_launch(void* const* d_in, const int* in_sizes, int n_in,
                              void* d_out, int out_size, void* d_ws, size_t ws_size,
                              hipStream_t stream)
{
  (void)in_sizes; (void)n_in;
  Net p;
  p.x = (const float*)d_in[0];
  p.c1a_w = (const float*)d_in[1];  p.c1a_b = (const float*)d_in[2];
  p.g1a = (const float*)d_in[3];    p.b1a = (const float*)d_in[4];
  p.m1a = (const float*)d_in[5];    p.v1a = (const float*)d_in[6];
  p.c1b_w = (const float*)d_in[7];  p.c1b_b = (const float*)d_in[8];
  p.g1b = (const float*)d_in[9];    p.b1b = (const float*)d_in[10];
  p.m1b = (const float*)d_in[11];   p.v1b = (const float*)d_in[12];
  p.c2a_w = (const float*)d_in[13]; p.c2a_b = (const float*)d_in[14];
  p.g2a = (const float*)d_in[15];   p.b2a = (const float*)d_in[16];
  p.m2a = (const float*)d_in[17];   p.v2a = (const float*)d_in[18];
  p.c2b_w = (const float*)d_in[19]; p.c2b_b = (const float*)d_in[20];
  p.g2b = (const float*)d_in[21];   p.b2b = (const float*)d_in[22];
  p.m2b = (const float*)d_in[23];   p.v2b = (const float*)d_in[24];
  for (int i = 0; i < 3; ++i) {
    p.qw[i] = (const float*)d_in[25 + 4 * i];
    p.qb[i] = (const float*)d_in[26 + 4 * i];
    p.rw[i] = (const float*)d_in[27 + 4 * i];
    p.rb[i] = (const float*)d_in[28 + 4 * i];
  }
  p.wih = (const float*)d_in[37]; p.whh = (const float*)d_in[38];
  p.bih = (const float*)d_in[39]; p.bhh = (const float*)d_in[40];
  p.fcw = (const float*)d_in[41]; p.fcb = (const float*)d_in[42];
  float* out = (float*)d_out;
  char* base = (char*)d_ws;

  const size_t ZB_F32 = 268435456, ZB_BF16 = 134217728, Y1B = 67108864;
  const size_t STATS = 1048576 * 2 + 65536 + 2097152 * 2 + 65536;
  const size_t HI_NEED = ZB_F32 + Y1B + STATS;   // ~326 MiB
  const size_t LO_NEED = ZB_BF16 + Y1B + STATS;  // ~198 MiB

  if (ws_size >= HI_NEED) {
    float* z = (float*)base;
    u16* y1u = (u16*)(base + ZB_F32);
    float* scr = (float*)(base + ZB_F32);  // overlays y1u (dead after conv2)
    char* sb = base + ZB_F32 + Y1B;
    run_all<float>(p, z, y1u, scr,
                   (float*)sb, (float*)(sb + 1048576), (float*)(sb + 2097152),
                   (float*)(sb + 2162688), (float*)(sb + 4259840),
                   (float*)(sb + 6356992), out, stream);
  } else if (ws_size >= LO_NEED) {
    u16* z = (u16*)base;
    u16* y1u = (u16*)(base + ZB_BF16);
    float* scr = (float*)(base + ZB_BF16);  // overlays y1u (dead after conv2)
    char* sb = base + ZB_BF16 + Y1B;
    run_all<u16>(p, z, y1u, scr,
                 (float*)sb, (float*)(sb + 1048576), (float*)(sb + 2097152),
                 (float*)(sb + 2162688), (float*)(sb + 4259840),
                 (float*)(sb + 6356992), out, stream);
  } else {
    k_report<<<3, 256, 0, stream>>>(out, (float)(ws_size >> 20), out_size);
  }
}

// Round 5
// 41578.220 us; speedup vs baseline: 2.6457x; 1.9397x over previous
//
#include <hip/hip_runtime.h>
#include <math.h>

// ---------------------------------------------------------------------------
// SimAM-CNN + Mogrifier-LSTM (Round 5): fence-free persistent LSTM.
// Cross-block data via agent-scope relaxed atomics (sc0 sc1 -> LLC-coherent,
// L1/L2 bypass); weights via plain loads (stay in L2 across steps — no
// threadfence/buffer_inv anywhere). Grid 512 = 2 blocks/CU co-resident.
// xl[b,t,:] = z + b*524288 + t*4096 (flat NCHW reinterpret).
// ---------------------------------------------------------------------------

typedef unsigned short u16;
typedef unsigned long long u64;

#define EPSBN 1e-5f

__device__ __forceinline__ float sigf(float x) { return 1.0f / (1.0f + expf(-x)); }

__device__ __forceinline__ float b2f(u16 u) {
  union { unsigned int i; float f; } v; v.i = ((unsigned int)u) << 16; return v.f;
}
__device__ __forceinline__ u16 f2b(float f) {
  union { float f; unsigned int i; } v; v.f = f;
  unsigned int r = v.i + 0x7FFFu + ((v.i >> 16) & 1u);
  return (u16)(r >> 16);
}

template <typename T> __device__ __forceinline__ float ld1(const T* p);
template <> __device__ __forceinline__ float ld1<float>(const float* p) { return *p; }
template <> __device__ __forceinline__ float ld1<u16>(const u16* p) { return b2f(*p); }
template <typename T> __device__ __forceinline__ void st1(T* p, float v);
template <> __device__ __forceinline__ void st1<float>(float* p, float v) { *p = v; }
template <> __device__ __forceinline__ void st1<u16>(u16* p, float v) { *p = f2b(v); }

// plain 2-element load (float or bf16)
template <typename T> __device__ __forceinline__ float2 ld2p(const T* p);
template <> __device__ __forceinline__ float2 ld2p<float>(const float* p) {
  return *(const float2*)p;
}
template <> __device__ __forceinline__ float2 ld2p<u16>(const u16* p) {
  unsigned int u = *(const unsigned int*)p;
  return make_float2(b2f((u16)(u & 0xffffu)), b2f((u16)(u >> 16)));
}

// ---- agent-scope (sc0 sc1) data path: coherent at LLC, bypasses L1/L2 ----
__device__ __forceinline__ float ld_sc(const float* p) {
  return __hip_atomic_load(p, __ATOMIC_RELAXED, __HIP_MEMORY_SCOPE_AGENT);
}
__device__ __forceinline__ void st_sc(float* p, float v) {
  __hip_atomic_store(p, v, __ATOMIC_RELAXED, __HIP_MEMORY_SCOPE_AGENT);
}
__device__ __forceinline__ float2 ld_sc2(const float* p) {
  union { u64 u; float2 f; } v;
  v.u = __hip_atomic_load((const u64*)p, __ATOMIC_RELAXED,
                          __HIP_MEMORY_SCOPE_AGENT);
  return v.f;
}
__device__ __forceinline__ void st_sc2(float* p, float2 f) {
  union { float2 f; u64 u; } v; v.f = f;
  __hip_atomic_store((u64*)p, v.u, __ATOMIC_RELAXED, __HIP_MEMORY_SCOPE_AGENT);
}

__device__ __forceinline__ float dot4(float4 a, float4 b) {
  return a.x * b.x + a.y * b.y + a.z * b.z + a.w * b.w;
}

__device__ __forceinline__ float simam_elem(float xv, float s, float ss) {
  float mu = (s - xv) * (1.0f / 8191.0f);
  float var = (ss - xv * xv - 8191.0f * mu * mu) * (1.0f / 8190.0f);
  float einv = ((xv - mu) * (xv - mu) + 2.0f * var + 0.2f) / (4.0f * (var + 0.1f));
  return xv * sigf(einv);
}

// --------------------------- CNN stage 1 (R2-verified) ----------------------
__global__ __launch_bounds__(256) void k_conv1(
    const float* __restrict__ x,
    const float* __restrict__ w1a, const float* __restrict__ b1a,
    const float* __restrict__ g1a, const float* __restrict__ bb1a,
    const float* __restrict__ m1a, const float* __restrict__ v1a,
    const float* __restrict__ w1b, const float* __restrict__ b1b,
    const float* __restrict__ g1b, const float* __restrict__ bb1b,
    const float* __restrict__ m1b, const float* __restrict__ v1b,
    u16* __restrict__ y1u, float* __restrict__ ps1, float* __restrict__ pss1)
{
  __shared__ float xs[6][66];
  __shared__ float a1[32][6][66];
  __shared__ float A1[32], T1[32], S2[32], T2[32];
  __shared__ float reds[4][32], redq[4][32];
  const int tid = threadIdx.x;
  const int b = blockIdx.x, t0 = blockIdx.y * 4;
  if (tid < 32) {
    float s = g1a[tid] * rsqrtf(v1a[tid] + EPSBN);
    A1[tid] = w1a[tid] * s;
    T1[tid] = (b1a[tid] - m1a[tid]) * s + bb1a[tid];
    float s2 = g1b[tid] * rsqrtf(v1b[tid] + EPSBN);
    S2[tid] = s2;
    T2[tid] = (b1b[tid] - m1b[tid]) * s2 + bb1b[tid];
  }
  for (int i = tid; i < 6 * 66; i += 256) {
    int r = i / 66, cc = i - r * 66;
    int t = t0 + r - 1, d = cc - 1;
    float v = 0.f;
    if (t >= 0 && t < 128 && d >= 0 && d < 64) v = x[(b * 128 + t) * 64 + d];
    xs[r][cc] = v;
  }
  __syncthreads();
  for (int i = tid; i < 32 * 6 * 66; i += 256) {
    int c = i / 396;
    int rr = i - c * 396;
    int r = rr / 66, cc = rr - r * 66;
    int t = t0 + r - 1, d = cc - 1;
    float v = 0.f;
    if (t >= 0 && t < 128 && d >= 0 && d < 64)
      v = fmaxf(xs[r][cc] * A1[c] + T1[c], 0.f);
    a1[c][r][cc] = v;
  }
  __syncthreads();
  const int d = tid & 63, tq = tid >> 6, lane = tid & 63;
  float acc[32];
#pragma unroll
  for (int i = 0; i < 32; ++i) acc[i] = 0.f;
#pragma unroll 1
  for (int c1 = 0; c1 < 32; ++c1) {
#pragma unroll
    for (int dt = 0; dt < 3; ++dt) {
      float av0 = a1[c1][tq + dt][d];
      float av1 = a1[c1][tq + dt][d + 1];
      float av2 = a1[c1][tq + dt][d + 2];
#pragma unroll
      for (int c2 = 0; c2 < 32; ++c2) {
        const float* wp = w1b + ((c2 * 32 + c1) * 3 + dt) * 3;  // uniform
        acc[c2] += av0 * wp[0] + av1 * wp[1] + av2 * wp[2];
      }
    }
  }
  const size_t ob = (size_t)b * 32 * 8192 + (size_t)(t0 + tq) * 64 + d;
#pragma unroll
  for (int c2 = 0; c2 < 32; ++c2) {
    float v = fmaxf(acc[c2] * S2[c2] + T2[c2], 0.f);
    y1u[ob + (size_t)c2 * 8192] = f2b(v);
    float s = v, q = v * v;
#pragma unroll
    for (int off = 32; off; off >>= 1) {
      s += __shfl_down(s, off);
      q += __shfl_down(q, off);
    }
    if (lane == 0) { reds[tq][c2] = s; redq[tq][c2] = q; }
  }
  __syncthreads();
  if (tid < 32) {
    float s = (reds[0][tid] + reds[1][tid]) + (reds[2][tid] + reds[3][tid]);
    float q = (redq[0][tid] + redq[1][tid]) + (redq[2][tid] + redq[3][tid]);
    ps1[(size_t)((b * 32 + tid) << 5) + blockIdx.y] = s;
    pss1[(size_t)((b * 32 + tid) << 5) + blockIdx.y] = q;
  }
}

__global__ __launch_bounds__(256) void k_red(
    const float* __restrict__ ps, const float* __restrict__ pss,
    float* __restrict__ stats, int npart, int nplanes)
{
  int p = blockIdx.x * 256 + threadIdx.x;
  if (p >= nplanes) return;
  float s = 0.f, q = 0.f;
  for (int j = 0; j < npart; ++j) {
    s += ps[(size_t)p * npart + j];
    q += pss[(size_t)p * npart + j];
  }
  stats[p] = s;
  stats[nplanes + p] = q;
}

template <typename T>
__global__ __launch_bounds__(256) void k_simam_t(
    T* __restrict__ buf, const float* __restrict__ stats, int nplanes)
{
  const int p = blockIdx.x, tid = threadIdx.x;
  T* base = buf + (size_t)p * 8192;
  const float s = stats[p], ss = stats[nplanes + p];
#pragma unroll 4
  for (int i = 0; i < 32; ++i) {
    int idx = tid + i * 256;
    float v = ld1(base + idx);
    st1(base + idx, simam_elem(v, s, ss));
  }
}

// --------------------------- CNN stage 2 (R2-verified) ----------------------
template <typename ZT>
__global__ __launch_bounds__(256) void k_conv2(
    const u16* __restrict__ y1u,
    const float* __restrict__ w2a, const float* __restrict__ b2a,
    const float* __restrict__ g2a, const float* __restrict__ bb2a,
    const float* __restrict__ m2a, const float* __restrict__ v2a,
    const float* __restrict__ w2b, const float* __restrict__ b2b,
    const float* __restrict__ g2b, const float* __restrict__ bb2b,
    const float* __restrict__ m2b, const float* __restrict__ v2b,
    ZT* __restrict__ z, float* __restrict__ ps2, float* __restrict__ pss2)
{
  __shared__ float y1s[32][4][66];
  __shared__ float a2[64][4][66];
  __shared__ float sA2a[64], sT2a[64], sA2b[64], sT2b[64];
  const int tid = threadIdx.x;
  const int t0 = blockIdx.x * 2, b = blockIdx.y;
  if (tid < 64) {
    float sa = g2a[tid] * rsqrtf(v2a[tid] + EPSBN);
    sA2a[tid] = sa;
    sT2a[tid] = (b2a[tid] - m2a[tid]) * sa + bb2a[tid];
    float sb = g2b[tid] * rsqrtf(v2b[tid] + EPSBN);
    sA2b[tid] = sb;
    sT2b[tid] = (b2b[tid] - m2b[tid]) * sb + bb2b[tid];
  }
  for (int i = tid; i < 32 * 4 * 66; i += 256) {
    int c1 = i / 264;
    int rr = i - c1 * 264;
    int r = rr / 66, cc = rr - r * 66;
    int t = t0 + r - 1, dd = cc - 1;
    float v = 0.f;
    if (t >= 0 && t < 128 && dd >= 0 && dd < 64)
      v = b2f(y1u[(size_t)(b * 32 + c1) * 8192 + t * 64 + dd]);
    y1s[c1][r][cc] = v;
  }
  __syncthreads();
  const int lane = tid & 63;
  const int c2base = __builtin_amdgcn_readfirstlane((int)(tid >> 6)) * 16;
#pragma unroll 1
  for (int i = 0; i < 16; ++i) {
    const int c2 = c2base + i;
    const float* wp = w2a + c2 * 32;  // uniform
    const float scl = sA2a[c2], off = sT2a[c2];
#pragma unroll 1
    for (int r = 0; r < 4; ++r) {
      for (int cc = lane; cc < 66; cc += 64) {
        float acc = 0.f;
#pragma unroll
        for (int c1 = 0; c1 < 32; ++c1) acc += y1s[c1][r][cc] * wp[c1];
        int t = t0 + r - 1, dd = cc - 1;
        float val = 0.f;
        if (t >= 0 && t < 128 && dd >= 0 && dd < 64)
          val = fmaxf(acc * scl + off, 0.f);
        a2[c2][r][cc] = val;
      }
    }
  }
  __syncthreads();
  const int d = tid & 63;
  const int gq = __builtin_amdgcn_readfirstlane((int)(tid >> 6));
  float acc[16][2];
#pragma unroll
  for (int i = 0; i < 16; ++i) { acc[i][0] = 0.f; acc[i][1] = 0.f; }
#pragma unroll 1
  for (int c1 = 0; c1 < 64; ++c1) {
    float a00 = a2[c1][0][d], a01 = a2[c1][0][d + 1], a02 = a2[c1][0][d + 2];
    float a10 = a2[c1][1][d], a11 = a2[c1][1][d + 1], a12 = a2[c1][1][d + 2];
    float a20 = a2[c1][2][d], a21 = a2[c1][2][d + 1], a22 = a2[c1][2][d + 2];
    float a30 = a2[c1][3][d], a31 = a2[c1][3][d + 1], a32 = a2[c1][3][d + 2];
#pragma unroll
    for (int i = 0; i < 16; ++i) {
      const float* wp = w2b + (size_t)((gq * 16 + i) * 64 + c1) * 9;  // uniform
      float w0 = wp[0], w1 = wp[1], w2 = wp[2];
      float w3 = wp[3], w4 = wp[4], w5 = wp[5];
      float w6 = wp[6], w7 = wp[7], w8 = wp[8];
      acc[i][0] += a00 * w0 + a01 * w1 + a02 * w2 + a10 * w3 + a11 * w4 +
                   a12 * w5 + a20 * w6 + a21 * w7 + a22 * w8;
      acc[i][1] += a10 * w0 + a11 * w1 + a12 * w2 + a20 * w3 + a21 * w4 +
                   a22 * w5 + a30 * w6 + a31 * w7 + a32 * w8;
    }
  }
#pragma unroll
  for (int i = 0; i < 16; ++i) {
    int c2 = gq * 16 + i;
    float sc = sA2b[c2], tb = sT2b[c2];
    float v0 = fmaxf(acc[i][0] * sc + tb, 0.f);
    float v1 = fmaxf(acc[i][1] * sc + tb, 0.f);
    size_t ob = (size_t)(b * 64 + c2) * 8192 + (size_t)t0 * 64 + d;
    st1(z + ob, v0);
    st1(z + ob + 64, v1);
    float s = v0 + v1, q = v0 * v0 + v1 * v1;
#pragma unroll
    for (int off = 32; off; off >>= 1) {
      s += __shfl_down(s, off);
      q += __shfl_down(q, off);
    }
    if (lane == 0) {
      ps2[(size_t)((b * 64 + c2) << 6) + blockIdx.x] = s;
      pss2[(size_t)((b * 64 + c2) << 6) + blockIdx.x] = q;
    }
  }
}

// --------------------------- persistent LSTM -------------------------------
// Fence-free grid barrier: relaxed atomics on 16 spread counters; no
// threadfence (no buffer_wbl2/buffer_inv -> weights stay cached in L2).
__device__ __forceinline__ void gridbar(unsigned* cnt, unsigned target) {
  asm volatile("" ::: "memory");
  __syncthreads();  // all waves' sc-stores issued before this have vmcnt=0
  if (threadIdx.x == 0)
    __hip_atomic_fetch_add(&cnt[(blockIdx.x & 15) * 64], 1u,
                           __ATOMIC_RELAXED, __HIP_MEMORY_SCOPE_AGENT);
  if (threadIdx.x < 64) {
    int lane = threadIdx.x;
    for (;;) {
      unsigned v = 0;
      if (lane < 16)
        v = __hip_atomic_load(&cnt[lane * 64], __ATOMIC_RELAXED,
                              __HIP_MEMORY_SCOPE_AGENT);
      v += __shfl_xor(v, 1);
      v += __shfl_xor(v, 2);
      v += __shfl_xor(v, 4);
      v += __shfl_xor(v, 8);
      v = __shfl(v, 0);
      if (v >= target) break;
      __builtin_amdgcn_s_sleep(2);
    }
  }
  __syncthreads();
  asm volatile("" ::: "memory");
}

// q: xm[b,n] = 2*sigmoid(hsrc[b,:256].qw[n,:] + qb[n]) * xin[b,n]
// grid split: nt=blk&127 (32 n), bt=blk>>7 (32 b). thread: 2n x 8b, 4-way
// lane K-split, hsrc staged in LDS (swizzled).
template <typename ZT, bool XSC>
__device__ __forceinline__ void q_phase(
    const float* __restrict__ qw, const float* __restrict__ qb,
    const float* __restrict__ hsrc, const ZT* __restrict__ xin,
    size_t xstride, float* __restrict__ xm, float* __restrict__ smem,
    int blk, int tid)
{
  const int nt = blk & 127, bt = blk >> 7;
  for (int i = tid; i < 4096; i += 256) {
    int row = i >> 7, c2 = i & 127;
    float2 v = ld_sc2(hsrc + (size_t)(bt * 32 + row) * 256 + c2 * 2);
    int col = c2 * 2;
    int sc = col ^ (((col >> 6) & 3) << 3);
    *(float2*)&smem[row * 256 + sc] = v;
  }
  __syncthreads();
  const int lane = tid & 63, w = tid >> 6;
  const int ns = lane & 15, ksub = lane >> 4;
  const int n0 = nt * 32 + ns * 2;
  const int b0 = bt * 32 + w * 8;
  float acc[2][8];
#pragma unroll
  for (int i = 0; i < 2; ++i)
#pragma unroll
    for (int j = 0; j < 8; ++j) acc[i][j] = 0.f;
  const float* w0p = qw + (size_t)n0 * 256 + ksub * 64;
  const float* w1p = w0p + 256;
#pragma unroll 2
  for (int k = 0; k < 64; k += 4) {
    float4 wv0 = *(const float4*)(w0p + k);
    float4 wv1 = *(const float4*)(w1p + k);
    int col = ksub * 64 + k;
    int sc = col ^ (ksub << 3);
#pragma unroll
    for (int j = 0; j < 8; ++j) {
      float4 hv = *(const float4*)&smem[(w * 8 + j) * 256 + sc];
      acc[0][j] += dot4(wv0, hv);
      acc[1][j] += dot4(wv1, hv);
    }
  }
#pragma unroll
  for (int i = 0; i < 2; ++i)
#pragma unroll
    for (int j = 0; j < 8; ++j) {
      acc[i][j] += __shfl_xor(acc[i][j], 16);
      acc[i][j] += __shfl_xor(acc[i][j], 32);
    }
  if (ksub == 0) {
    float bq0 = qb[n0], bq1 = qb[n0 + 1];
#pragma unroll
    for (int j = 0; j < 8; ++j) {
      size_t bi = (size_t)(b0 + j);
      float2 xv;
      if (XSC) xv = ld_sc2(((const float*)xin) + bi * xstride + n0);
      else     xv = ld2p(xin + bi * xstride + n0);
      float2 o = make_float2(2.f * sigf(acc[0][j] + bq0) * xv.x,
                             2.f * sigf(acc[1][j] + bq1) * xv.y);
      st_sc2(xm + bi * 4096 + n0, o);
    }
  }
}

// r: hm[b,n] = 2*sigmoid(xm[b,:4096].rw[n,:] + rb[n]) * src[b,n]
// grid: nt=blk&31 (8 n), bt=blk>>5 (8 b). thread: 4n x 1b, 16-way K-split
// per 512-chunk; xm chunk staged in LDS (stride 516 + xor swizzle).
__device__ __forceinline__ void r_phase(
    const float* __restrict__ rw, const float* __restrict__ rb,
    const float* __restrict__ src, const float* __restrict__ xm,
    float* __restrict__ hm, float* __restrict__ smem, int blk, int tid)
{
  const int nt = blk & 31, bt = blk >> 5;
  const int lane = tid & 63, w = tid >> 6;
  const int bs = lane & 3, ksub = lane >> 2;
  const int n0 = nt * 8 + (w & 1) * 4;
  const int rrow = (w >> 1) * 4 + bs;  // local b row 0..7
  float acc[4] = {0.f, 0.f, 0.f, 0.f};
  const float* wr0 = rw + (size_t)n0 * 4096;
#pragma unroll 1
  for (int kc = 0; kc < 8; ++kc) {
    __syncthreads();
    for (int i = tid; i < 2048; i += 256) {
      int row = i >> 8, c2 = i & 255;
      float2 v = ld_sc2(xm + (size_t)(bt * 8 + row) * 4096 + kc * 512 + c2 * 2);
      int col = c2 * 2;
      int sc = col ^ (((col >> 5) & 3) << 3);
      *(float2*)&smem[row * 516 + sc] = v;
    }
    __syncthreads();
    const int kb = kc * 512 + ksub * 32;
#pragma unroll
    for (int k = 0; k < 32; k += 4) {
      int col = ksub * 32 + k;
      int sc = col ^ (((col >> 5) & 3) << 3);
      float4 xv = *(const float4*)&smem[rrow * 516 + sc];
      float4 wv0 = *(const float4*)(wr0 + kb + k);
      float4 wv1 = *(const float4*)(wr0 + 4096 + kb + k);
      float4 wv2 = *(const float4*)(wr0 + 8192 + kb + k);
      float4 wv3 = *(const float4*)(wr0 + 12288 + kb + k);
      acc[0] += dot4(wv0, xv);
      acc[1] += dot4(wv1, xv);
      acc[2] += dot4(wv2, xv);
      acc[3] += dot4(wv3, xv);
    }
  }
#pragma unroll
  for (int i = 0; i < 4; ++i) {
    acc[i] += __shfl_xor(acc[i], 4);
    acc[i] += __shfl_xor(acc[i], 8);
    acc[i] += __shfl_xor(acc[i], 16);
    acc[i] += __shfl_xor(acc[i], 32);
  }
  if (ksub == 0) {
    int b = bt * 8 + rrow;
    size_t idx = (size_t)b * 256 + n0;
    float2 s0 = ld_sc2(src + idx), s1 = ld_sc2(src + idx + 2);
    float2 o0 = make_float2(2.f * sigf(acc[0] + rb[n0]) * s0.x,
                            2.f * sigf(acc[1] + rb[n0 + 1]) * s0.y);
    float2 o1 = make_float2(2.f * sigf(acc[2] + rb[n0 + 2]) * s1.x,
                            2.f * sigf(acc[3] + rb[n0 + 3]) * s1.y);
    st_sc2(hm + idx, o0);
    st_sc2(hm + idx + 2, o1);
  }
}

// gates partials: grid: nt=blk&15 (64 n), bg=(blk>>4)&1 (64 b), ks=blk>>5
// (16 K-chunks of 256). thread: 4n x 4b full-chunk-K. ks==0 also does whh.
__device__ __forceinline__ void g_phase(
    const float* __restrict__ wih, const float* __restrict__ whh,
    const float* __restrict__ xm, const float* __restrict__ hm,
    float* __restrict__ gslab, float* __restrict__ smem, int blk, int tid)
{
  const int nt = blk & 15, bg = (blk >> 4) & 1, ks = blk >> 5;
  const int nsub = tid & 15, bsub = tid >> 4;
  const int n0 = nt * 64 + nsub * 4;
  const int b0l = bsub * 4;
  for (int i = tid; i < 8192; i += 256) {
    int row = i >> 7, c2 = i & 127;
    float2 v = ld_sc2(xm + (size_t)(bg * 64 + row) * 4096 + ks * 256 + c2 * 2);
    *(float2*)&smem[row * 260 + c2 * 2] = v;
  }
  __syncthreads();
  float acc[4][4];
#pragma unroll
  for (int i = 0; i < 4; ++i)
#pragma unroll
    for (int j = 0; j < 4; ++j) acc[i][j] = 0.f;
  const float* wb = wih + (size_t)n0 * 4096 + ks * 256;
#pragma unroll 2
  for (int k = 0; k < 256; k += 4) {
    float4 wv0 = *(const float4*)(wb + k);
    float4 wv1 = *(const float4*)(wb + 4096 + k);
    float4 wv2 = *(const float4*)(wb + 8192 + k);
    float4 wv3 = *(const float4*)(wb + 12288 + k);
#pragma unroll
    for (int j = 0; j < 4; ++j) {
      float4 xv = *(const float4*)&smem[(b0l + j) * 260 + k];
      acc[0][j] += dot4(wv0, xv);
      acc[1][j] += dot4(wv1, xv);
      acc[2][j] += dot4(wv2, xv);
      acc[3][j] += dot4(wv3, xv);
    }
  }
  {
    float* gs = gslab + (size_t)ks * 131072;
#pragma unroll
    for (int j = 0; j < 4; ++j) {
      float* p = gs + (size_t)(bg * 64 + b0l + j) * 1024 + n0;
      st_sc2(p, make_float2(acc[0][j], acc[1][j]));
      st_sc2(p + 2, make_float2(acc[2][j], acc[3][j]));
    }
  }
  if (ks == 0) {  // block-uniform branch: whh contribution -> slab 16
    __syncthreads();
    for (int i = tid; i < 8192; i += 256) {
      int row = i >> 7, c2 = i & 127;
      float2 v = ld_sc2(hm + (size_t)(bg * 64 + row) * 256 + c2 * 2);
      *(float2*)&smem[row * 260 + c2 * 2] = v;
    }
    __syncthreads();
    float a2[4][4];
#pragma unroll
    for (int i = 0; i < 4; ++i)
#pragma unroll
      for (int j = 0; j < 4; ++j) a2[i][j] = 0.f;
    const float* vb = whh + (size_t)n0 * 256;
#pragma unroll 2
    for (int k = 0; k < 256; k += 4) {
      float4 wv0 = *(const float4*)(vb + k);
      float4 wv1 = *(const float4*)(vb + 256 + k);
      float4 wv2 = *(const float4*)(vb + 512 + k);
      float4 wv3 = *(const float4*)(vb + 768 + k);
#pragma unroll
      for (int j = 0; j < 4; ++j) {
        float4 xv = *(const float4*)&smem[(b0l + j) * 260 + k];
        a2[0][j] += dot4(wv0, xv);
        a2[1][j] += dot4(wv1, xv);
        a2[2][j] += dot4(wv2, xv);
        a2[3][j] += dot4(wv3, xv);
      }
    }
    float* gs = gslab + (size_t)16 * 131072;
#pragma unroll
    for (int j = 0; j < 4; ++j) {
      float* p = gs + (size_t)(bg * 64 + b0l + j) * 1024 + n0;
      st_sc2(p, make_float2(a2[0][j], a2[1][j]));
      st_sc2(p + 2, make_float2(a2[2][j], a2[3][j]));
    }
  }
}

// finalize gates -> h (global, sc) and c (register, block-private)
__device__ __forceinline__ void hfin_phase(
    const float* __restrict__ gslab, const float* __restrict__ bih,
    const float* __restrict__ bhh, float* __restrict__ h, float& c_reg,
    int blk, int tid)
{
  if (blk >= 128) return;
  const int kk = tid;
  float gi = bih[kk] + bhh[kk];
  float gf = bih[kk + 256] + bhh[kk + 256];
  float gg = bih[kk + 512] + bhh[kk + 512];
  float go = bih[kk + 768] + bhh[kk + 768];
  const float* base = gslab + (size_t)blk * 1024 + kk;
#pragma unroll 1
  for (int s = 0; s < 17; ++s) {
    const float* gp = base + (size_t)s * 131072;
    gi += ld_sc(gp);
    gf += ld_sc(gp + 256);
    gg += ld_sc(gp + 512);
    go += ld_sc(gp + 768);
  }
  float cn = sigf(gf) * c_reg + sigf(gi) * tanhf(gg);
  c_reg = cn;
  st_sc(h + blk * 256 + kk, sigf(go) * tanhf(cn));
}

template <typename ZT>
__global__ __launch_bounds__(256, 2) void k_lstm(
    const ZT* __restrict__ z,
    const float* __restrict__ q0w, const float* __restrict__ q0b,
    const float* __restrict__ r0w, const float* __restrict__ r0b,
    const float* __restrict__ q1w, const float* __restrict__ q1b,
    const float* __restrict__ r1w, const float* __restrict__ r1b,
    const float* __restrict__ q2w, const float* __restrict__ q2b,
    const float* __restrict__ r2w, const float* __restrict__ r2b,
    const float* __restrict__ wih, const float* __restrict__ whh,
    const float* __restrict__ bih, const float* __restrict__ bhh,
    const float* __restrict__ fcw, const float* __restrict__ fcb,
    float* __restrict__ xm, float* __restrict__ h,
    float* __restrict__ hm, float* __restrict__ gslab,
    unsigned* __restrict__ cnt, float* __restrict__ out)
{
  __shared__ float smem[16640];  // 66,560 B: q 32x256 / r 8x516 / g 64x260
  const int blk = blockIdx.x, tid = threadIdx.x;
  float c_reg = 0.f;
  unsigned ep = 0;
#pragma unroll 1
  for (int t = 0; t < 128; ++t) {
    q_phase<ZT, false>(q0w, q0b, h, z + (size_t)t * 4096, 524288, xm, smem, blk, tid);
    gridbar(cnt, (++ep) * 512u);
    r_phase(r0w, r0b, h, xm, hm, smem, blk, tid);
    gridbar(cnt, (++ep) * 512u);
    q_phase<float, true>(q1w, q1b, hm, xm, 4096, xm, smem, blk, tid);
    gridbar(cnt, (++ep) * 512u);
    r_phase(r1w, r1b, hm, xm, hm, smem, blk, tid);
    gridbar(cnt, (++ep) * 512u);
    q_phase<float, true>(q2w, q2b, hm, xm, 4096, xm, smem, blk, tid);
    gridbar(cnt, (++ep) * 512u);
    r_phase(r2w, r2b, hm, xm, hm, smem, blk, tid);
    gridbar(cnt, (++ep) * 512u);
    g_phase(wih, whh, xm, hm, gslab, smem, blk, tid);
    gridbar(cnt, (++ep) * 512u);
    hfin_phase(gslab, bih, bhh, h, c_reg, blk, tid);
    gridbar(cnt, (++ep) * 512u);
  }
  // FC: block blk (<128) reads its own h row (written by own block's sc stores)
  if (blk < 128 && tid < 5) {
    float acc = fcb[tid];
    const float* hr = h + blk * 256;
    const float* wr = fcw + (size_t)tid * 256;
    for (int k = 0; k < 256; ++k) acc += ld_sc(hr + k) * wr[k];
    out[blk * 5 + tid] = acc;
  }
}

__global__ __launch_bounds__(256) void k_report(float* out, float v, int n) {
  int i = blockIdx.x * 256 + threadIdx.x;
  if (i < n) out[i] = v;
}

// ---------------------------------------------------------------------------
struct Net {
  const float *x;
  const float *c1a_w, *c1a_b, *g1a, *b1a, *m1a, *v1a;
  const float *c1b_w, *c1b_b, *g1b, *b1b, *m1b, *v1b;
  const float *c2a_w, *c2a_b, *g2a, *b2a, *m2a, *v2a;
  const float *c2b_w, *c2b_b, *g2b, *b2b, *m2b, *v2b;
  const float *qw[3], *qb[3], *rw[3], *rb[3];
  const float *wih, *whh, *bih, *bhh, *fcw, *fcb;
};

template <typename ZT>
static void run_all(const Net& p, ZT* z, u16* y1u, float* scr,
                    float* ps1, float* pss1, float* st1v,
                    float* ps2, float* pss2, float* st2v,
                    float* out, hipStream_t stream)
{
  float* xm    = scr;             // 524,288 floats
  float* h     = scr + 524288;    // 32,768
  float* hm    = scr + 557056;    // 32,768
  float* gslab = scr + 589824;    // 17 * 131,072 = 2,228,224
  unsigned* cnt = (unsigned*)(scr + 2818048);  // 16 counters, 256B apart

  k_conv1<<<dim3(128, 32), 256, 0, stream>>>(p.x, p.c1a_w, p.c1a_b, p.g1a,
      p.b1a, p.m1a, p.v1a, p.c1b_w, p.c1b_b, p.g1b, p.b1b, p.m1b, p.v1b,
      y1u, ps1, pss1);
  k_red<<<16, 256, 0, stream>>>(ps1, pss1, st1v, 32, 4096);
  k_simam_t<u16><<<4096, 256, 0, stream>>>(y1u, st1v, 4096);
  k_conv2<ZT><<<dim3(64, 128), 256, 0, stream>>>(y1u, p.c2a_w, p.c2a_b, p.g2a,
      p.b2a, p.m2a, p.v2a, p.c2b_w, p.c2b_b, p.g2b, p.b2b, p.m2b, p.v2b,
      z, ps2, pss2);
  k_red<<<32, 256, 0, stream>>>(ps2, pss2, st2v, 64, 8192);
  k_simam_t<ZT><<<8192, 256, 0, stream>>>(z, st2v, 8192);

  hipMemsetAsync(h, 0, 32768 * sizeof(float), stream);  // h(t=0) = 0
  hipMemsetAsync(cnt, 0, 16 * 64 * sizeof(unsigned), stream);

  k_lstm<ZT><<<512, 256, 0, stream>>>(z,
      p.qw[0], p.qb[0], p.rw[0], p.rb[0],
      p.qw[1], p.qb[1], p.rw[1], p.rb[1],
      p.qw[2], p.qb[2], p.rw[2], p.rb[2],
      p.wih, p.whh, p.bih, p.bhh, p.fcw, p.fcb,
      xm, h, hm, gslab, cnt, out);
}

extern "C" void kernel_launch(void* const* d_in, const int* in_sizes, int n_in,
                              void* d_out, int out_size, void* d_ws, size_t ws_size,
                              hipStream_t stream)
{
  (void)in_sizes; (void)n_in;
  Net p;
  p.x = (const float*)d_in[0];
  p.c1a_w = (const float*)d_in[1];  p.c1a_b = (const float*)d_in[2];
  p.g1a = (const float*)d_in[3];    p.b1a = (const float*)d_in[4];
  p.m1a = (const float*)d_in[5];    p.v1a = (const float*)d_in[6];
  p.c1b_w = (const float*)d_in[7];  p.c1b_b = (const float*)d_in[8];
  p.g1b = (const float*)d_in[9];    p.b1b = (const float*)d_in[10];
  p.m1b = (const float*)d_in[11];   p.v1b = (const float*)d_in[12];
  p.c2a_w = (const float*)d_in[13]; p.c2a_b = (const float*)d_in[14];
  p.g2a = (const float*)d_in[15];   p.b2a = (const float*)d_in[16];
  p.m2a = (const float*)d_in[17];   p.v2a = (const float*)d_in[18];
  p.c2b_w = (const float*)d_in[19]; p.c2b_b = (const float*)d_in[20];
  p.g2b = (const float*)d_in[21];   p.b2b = (const float*)d_in[22];
  p.m2b = (const float*)d_in[23];   p.v2b = (const float*)d_in[24];
  for (int i = 0; i < 3; ++i) {
    p.qw[i] = (const float*)d_in[25 + 4 * i];
    p.qb[i] = (const float*)d_in[26 + 4 * i];
    p.rw[i] = (const float*)d_in[27 + 4 * i];
    p.rb[i] = (const float*)d_in[28 + 4 * i];
  }
  p.wih = (const float*)d_in[37]; p.whh = (const float*)d_in[38];
  p.bih = (const float*)d_in[39]; p.bhh = (const float*)d_in[40];
  p.fcw = (const float*)d_in[41]; p.fcb = (const float*)d_in[42];
  float* out = (float*)d_out;
  char* base = (char*)d_ws;

  const size_t ZB_F32 = 268435456, ZB_BF16 = 134217728, Y1B = 67108864;
  const size_t STATS = 1048576 * 2 + 65536 + 2097152 * 2 + 65536;
  const size_t HI_NEED = ZB_F32 + Y1B + STATS;   // ~326 MiB
  const size_t LO_NEED = ZB_BF16 + Y1B + STATS;  // ~198 MiB

  if (ws_size >= HI_NEED) {
    float* z = (float*)base;
    u16* y1u = (u16*)(base + ZB_F32);
    float* scr = (float*)(base + ZB_F32);  // overlays y1u (dead after conv2)
    char* sb = base + ZB_F32 + Y1B;
    run_all<float>(p, z, y1u, scr,
                   (float*)sb, (float*)(sb + 1048576), (float*)(sb + 2097152),
                   (float*)(sb + 2162688), (float*)(sb + 4259840),
                   (float*)(sb + 6356992), out, stream);
  } else if (ws_size >= LO_NEED) {
    u16* z = (u16*)base;
    u16* y1u = (u16*)(base + ZB_BF16);
    float* scr = (float*)(base + ZB_BF16);  // overlays y1u (dead after conv2)
    char* sb = base + ZB_BF16 + Y1B;
    run_all<u16>(p, z, y1u, scr,
                 (float*)sb, (float*)(sb + 1048576), (float*)(sb + 2097152),
                 (float*)(sb + 2162688), (float*)(sb + 4259840),
                 (float*)(sb + 6356992), out, stream);
  } else {
    k_report<<<3, 256, 0, stream>>>(out, (float)(ws_size >> 20), out_size);
  }
}